// Round 5
// baseline (208.076 us; speedup 1.0000x reference)
//
#include <hip/hip_runtime.h>

// N=1e6 points x 32 fp32 (16 outer + 16 inner dims), 64 outer centers, 8 inner each.
// out[p] = argmin_inner + 8*argmin_outer (int32).
//
// Single self-contained kernel: R4's two-kernel d_ws handoff diverged under graph
// replay (cross-XCD L2 non-coherence between graph nodes) — all prep is per-block.
constexpr int D = 16;
constexpr int NC = 64;
constexpr int NCPC = 8;
constexpr int OSTRIDE = NCPC * D + 4;   // 132 floats: stagger start bank by outer idx, 16B aligned
constexpr int NPT = 2;                  // points per thread (x stays in VGPRs)
constexpr int BLOCK = 256;

typedef float v2f __attribute__((ext_vector_type(2)));

__device__ __forceinline__ float lane_bcast(float v, int lane) {
    // v_readlane_b32: broadcast lane's value through an SGPR. 1 issue, no LDS pipe.
    return __int_as_float(__builtin_amdgcn_readlane(__float_as_int(v), lane));
}

__global__ __launch_bounds__(BLOCK, 4)
void cluster_kernel(const float* __restrict__ x,
                    const float* __restrict__ co,
                    const float* __restrict__ ci,
                    int* __restrict__ out, int n)
{
    // LDS: inner centers (divergent phase-2 gather) + halved norms. ~36 KB -> 4 blocks/CU.
    __shared__ __align__(16) float s_ci[NC * OSTRIDE];
    __shared__ float s_onorm[NC];               // 0.5*||co_j||^2
    __shared__ float s_inorm[NC * 9];           // 0.5*||ci_{o,k}||^2, [o][k] stride 9 (bank spread)

    const int t = threadIdx.x;

    // ---- Stage inner centers (2048 float4) into LDS, coalesced ----
    const float4* ci4 = (const float4*)ci;
#pragma unroll
    for (int i = 0; i < 8; ++i) {
        int idx = t + i * BLOCK;
        int o = idx >> 5;
        int f = idx & 31;
        *(float4*)&s_ci[o * OSTRIDE + f * 4] = ci4[idx];
    }
    // ---- 576 halved norms once per block (0.5x is exact: argmin order preserved) ----
    for (int i = t; i < NC + NC * NCPC; i += BLOCK) {
        const float* src = (i < NC) ? (co + i * D) : (ci + (size_t)(i - NC) * D);
        float s = 0.f;
#pragma unroll
        for (int k = 0; k < D; ++k) s = fmaf(src[k], src[k], s);
        s *= 0.5f;
        if (i < NC) s_onorm[i] = s;
        else { int ii = i - NC; s_inorm[(ii >> 3) * 9 + (ii & 7)] = s; }
    }
    __syncthreads();

    // Lane l holds 0.5*||c_l||^2; hot loop broadcasts lane j via readlane (no LDS in j-loop).
    float mynorm = s_onorm[t & 63];

    const int base = blockIdx.x * (BLOCK * NPT) + t;
    int p0 = base, p1 = base + BLOCK;
    bool v0 = p0 < n, v1 = p1 < n;
    if (!v0) p0 = n - 1;                 // clamp: uniform code path, store guarded
    if (!v1) p1 = n - 1;

    // ---- Load both points fully up front (one vmcnt burst). Store NEGATED:
    //      score = 0.5*||c||^2 + sum (-x)*c  ==  0.5*(||c||^2 - 2 x.c)  (exact scale) ----
    v2f  nx1[D];        // {-x1_pt0[k], -x1_pt1[k]} packed for v_pk_fma_f32
    float nx2[2][D];    // -x2 per point (phase 2 is per-point scalar)
    {
        const float4* a = (const float4*)(x + (size_t)p0 * 32);
        const float4* b = (const float4*)(x + (size_t)p1 * 32);
        float4 A0=a[0],A1=a[1],A2=a[2],A3=a[3],A4=a[4],A5=a[5],A6=a[6],A7=a[7];
        float4 B0=b[0],B1=b[1],B2=b[2],B3=b[3],B4=b[4],B5=b[5],B6=b[6],B7=b[7];
        nx1[0]  = (v2f){-A0.x,-B0.x}; nx1[1]  = (v2f){-A0.y,-B0.y};
        nx1[2]  = (v2f){-A0.z,-B0.z}; nx1[3]  = (v2f){-A0.w,-B0.w};
        nx1[4]  = (v2f){-A1.x,-B1.x}; nx1[5]  = (v2f){-A1.y,-B1.y};
        nx1[6]  = (v2f){-A1.z,-B1.z}; nx1[7]  = (v2f){-A1.w,-B1.w};
        nx1[8]  = (v2f){-A2.x,-B2.x}; nx1[9]  = (v2f){-A2.y,-B2.y};
        nx1[10] = (v2f){-A2.z,-B2.z}; nx1[11] = (v2f){-A2.w,-B2.w};
        nx1[12] = (v2f){-A3.x,-B3.x}; nx1[13] = (v2f){-A3.y,-B3.y};
        nx1[14] = (v2f){-A3.z,-B3.z}; nx1[15] = (v2f){-A3.w,-B3.w};
        nx2[0][0]=-A4.x;  nx2[0][1]=-A4.y;  nx2[0][2]=-A4.z;  nx2[0][3]=-A4.w;
        nx2[0][4]=-A5.x;  nx2[0][5]=-A5.y;  nx2[0][6]=-A5.z;  nx2[0][7]=-A5.w;
        nx2[0][8]=-A6.x;  nx2[0][9]=-A6.y;  nx2[0][10]=-A6.z; nx2[0][11]=-A6.w;
        nx2[0][12]=-A7.x; nx2[0][13]=-A7.y; nx2[0][14]=-A7.z; nx2[0][15]=-A7.w;
        nx2[1][0]=-B4.x;  nx2[1][1]=-B4.y;  nx2[1][2]=-B4.z;  nx2[1][3]=-B4.w;
        nx2[1][4]=-B5.x;  nx2[1][5]=-B5.y;  nx2[1][6]=-B5.z;  nx2[1][7]=-B5.w;
        nx2[1][8]=-B6.x;  nx2[1][9]=-B6.y;  nx2[1][10]=-B6.z; nx2[1][11]=-B6.w;
        nx2[1][12]=-B7.x; nx2[1][13]=-B7.y; nx2[1][14]=-B7.z; nx2[1][15]=-B7.w;
    }

    // ---- Phase 1: outer argmin. Raw centers via wave-uniform s_load (scalar pipe,
    //      zero VALU cost), software-pipelined cur/nxt. Norm seeds the pk_fma chain. ----
    float bd0 = 3.4e38f, bd1 = 3.4e38f;
    int bo0 = 0, bo1 = 0;

    float cur[D];
#pragma unroll
    for (int k = 0; k < D; ++k) cur[k] = co[k];

#pragma unroll 2
    for (int j = 0; j < NC; ++j) {
        float nxt[D];
        int jn = (j < NC - 1) ? (j + 1) : j;
#pragma unroll
        for (int k = 0; k < D; ++k) nxt[k] = co[jn * D + k];   // uniform -> s_load, indep of compute

        float nrm = lane_bcast(mynorm, j);                      // 0.5*||c_j||^2
        v2f acc = (v2f){nrm, nrm};
#pragma unroll
        for (int k = 0; k < D; ++k)
            acc = __builtin_elementwise_fma(nx1[k], (v2f){cur[k], cur[k]}, acc); // v_pk_fma_f32

        if (acc.x < bd0) { bd0 = acc.x; bo0 = j; }   // strict <: np.argmin first-index ties
        if (acc.y < bd1) { bd1 = acc.y; bo1 = j; }

#pragma unroll
        for (int k = 0; k < D; ++k) cur[k] = nxt[k];            // s_mov rotate (scalar pipe)
    }

    // ---- Phase 2: inner argmin (LDS gather by per-lane bo). Same seeding trick. ----
    int boA[2] = {bo0, bo1};
    int pA[2]  = {p0, p1};
    bool vA[2] = {v0, v1};
#pragma unroll
    for (int pt = 0; pt < 2; ++pt) {
        const float* cb = s_ci + boA[pt] * OSTRIDE;
        const float* nb = s_inorm + boA[pt] * 9;
        float nrm8[NCPC];
#pragma unroll
        for (int k = 0; k < NCPC; ++k) nrm8[k] = nb[k];         // 8 ds_read_b32, issued early
        float bd = 3.4e38f; int bk = 0;
#pragma unroll
        for (int k = 0; k < NCPC; ++k) {
            float4 c0 = *(const float4*)&cb[k * D + 0];
            float4 c1 = *(const float4*)&cb[k * D + 4];
            float4 c2 = *(const float4*)&cb[k * D + 8];
            float4 c3 = *(const float4*)&cb[k * D + 12];
            float acc = nrm8[k];                                // 0.5*||ci||^2 seeds chain
            acc = fmaf(nx2[pt][0],  c0.x, acc); acc = fmaf(nx2[pt][1],  c0.y, acc);
            acc = fmaf(nx2[pt][2],  c0.z, acc); acc = fmaf(nx2[pt][3],  c0.w, acc);
            acc = fmaf(nx2[pt][4],  c1.x, acc); acc = fmaf(nx2[pt][5],  c1.y, acc);
            acc = fmaf(nx2[pt][6],  c1.z, acc); acc = fmaf(nx2[pt][7],  c1.w, acc);
            acc = fmaf(nx2[pt][8],  c2.x, acc); acc = fmaf(nx2[pt][9],  c2.y, acc);
            acc = fmaf(nx2[pt][10], c2.z, acc); acc = fmaf(nx2[pt][11], c2.w, acc);
            acc = fmaf(nx2[pt][12], c3.x, acc); acc = fmaf(nx2[pt][13], c3.y, acc);
            acc = fmaf(nx2[pt][14], c3.z, acc); acc = fmaf(nx2[pt][15], c3.w, acc);
            if (acc < bd) { bd = acc; bk = k; }
        }
        if (vA[pt]) out[pA[pt]] = boA[pt] * NCPC + bk;
    }
}

extern "C" void kernel_launch(void* const* d_in, const int* in_sizes, int n_in,
                              void* d_out, int out_size, void* d_ws, size_t ws_size,
                              hipStream_t stream) {
    const float* x  = (const float*)d_in[0];   // (N, 32) fp32
    const float* co = (const float*)d_in[1];   // (64, 16) fp32
    const float* ci = (const float*)d_in[2];   // (64, 8, 16) fp32
    int* out = (int*)d_out;                    // (N,) int32
    int n = in_sizes[0] / 32;
    int blocks = (n + BLOCK * NPT - 1) / (BLOCK * NPT);
    cluster_kernel<<<blocks, BLOCK, 0, stream>>>(x, co, ci, out, n);
}

// Round 6
// 207.769 us; speedup vs baseline: 1.0015x; 1.0015x over previous
//
#include <hip/hip_runtime.h>

// N=1e6 points x 32 fp32 (16 outer + 16 inner dims), 64 outer centers, 8 inner each.
// out[p] = argmin_inner + 8*argmin_outer (int32).
//
// R6: BLOCK 256->512. LDS/block (36.3 KB) still allows 4 blocks/CU, so occupancy
// doubles to 32 waves/CU (100%); preamble count halves (977 blocks, ~3.8/CU).
// Negation of x folded into FMA neg-modifiers (free, bit-exact).
constexpr int D = 16;
constexpr int NC = 64;
constexpr int NCPC = 8;
constexpr int OSTRIDE = NCPC * D + 4;   // 132 floats: start bank = (o+4k)%32 -> gather spread
constexpr int NPT = 2;                  // points per thread (x stays in VGPRs)
constexpr int BLOCK = 512;

typedef float v2f __attribute__((ext_vector_type(2)));

__device__ __forceinline__ float lane_bcast(float v, int lane) {
    // v_readlane_b32: broadcast lane's value through an SGPR. 1 issue, no LDS pipe.
    return __int_as_float(__builtin_amdgcn_readlane(__float_as_int(v), lane));
}

__global__ __launch_bounds__(BLOCK, 8)   // 8 waves/EU = 4 blocks/CU co-resident
void cluster_kernel(const float* __restrict__ x,
                    const float* __restrict__ co,
                    const float* __restrict__ ci,
                    int* __restrict__ out, int n)
{
    // LDS: inner centers (divergent phase-2 gather) + halved norms. 36.3 KB -> 4 blocks/CU.
    __shared__ __align__(16) float s_ci[NC * OSTRIDE];
    __shared__ float s_onorm[NC];               // 0.5*||co_j||^2
    __shared__ float s_inorm[NC * 9];           // 0.5*||ci_{o,k}||^2, [o][k] stride 9 (bank spread)

    const int t = threadIdx.x;

    // ---- Stage inner centers (2048 float4) into LDS, coalesced ----
    const float4* ci4 = (const float4*)ci;
#pragma unroll
    for (int i = 0; i < 4; ++i) {
        int idx = t + i * BLOCK;        // 0..2047
        int o = idx >> 5;
        int f = idx & 31;
        *(float4*)&s_ci[o * OSTRIDE + f * 4] = ci4[idx];
    }
    // ---- 576 halved norms once per block (0.5x exact: argmin order preserved) ----
    for (int i = t; i < NC + NC * NCPC; i += BLOCK) {
        const float* src = (i < NC) ? (co + i * D) : (ci + (size_t)(i - NC) * D);
        float s = 0.f;
#pragma unroll
        for (int k = 0; k < D; ++k) s = fmaf(src[k], src[k], s);
        s *= 0.5f;
        if (i < NC) s_onorm[i] = s;
        else { int ii = i - NC; s_inorm[(ii >> 3) * 9 + (ii & 7)] = s; }
    }
    __syncthreads();

    // Lane l holds 0.5*||c_l||^2; hot loop broadcasts lane j via readlane (no LDS in j-loop).
    float mynorm = s_onorm[t & 63];

    const int base = blockIdx.x * (BLOCK * NPT) + t;
    int p0 = base, p1 = base + BLOCK;
    bool v0 = p0 < n, v1 = p1 < n;
    if (!v0) p0 = n - 1;                 // clamp: uniform code path, store guarded
    if (!v1) p1 = n - 1;

    // ---- Load both points fully up front (one vmcnt burst). x kept RAW; the
    //      score = 0.5*||c||^2 + sum (-x)*c uses free fma neg-modifiers. ----
    v2f  xx1[D];        // {x1_pt0[k], x1_pt1[k]} packed for v_pk_fma_f32
    float x2[2][D];
    {
        const float4* a = (const float4*)(x + (size_t)p0 * 32);
        const float4* b = (const float4*)(x + (size_t)p1 * 32);
        float4 A0=a[0],A1=a[1],A2=a[2],A3=a[3],A4=a[4],A5=a[5],A6=a[6],A7=a[7];
        float4 B0=b[0],B1=b[1],B2=b[2],B3=b[3],B4=b[4],B5=b[5],B6=b[6],B7=b[7];
        xx1[0]  = (v2f){A0.x,B0.x}; xx1[1]  = (v2f){A0.y,B0.y};
        xx1[2]  = (v2f){A0.z,B0.z}; xx1[3]  = (v2f){A0.w,B0.w};
        xx1[4]  = (v2f){A1.x,B1.x}; xx1[5]  = (v2f){A1.y,B1.y};
        xx1[6]  = (v2f){A1.z,B1.z}; xx1[7]  = (v2f){A1.w,B1.w};
        xx1[8]  = (v2f){A2.x,B2.x}; xx1[9]  = (v2f){A2.y,B2.y};
        xx1[10] = (v2f){A2.z,B2.z}; xx1[11] = (v2f){A2.w,B2.w};
        xx1[12] = (v2f){A3.x,B3.x}; xx1[13] = (v2f){A3.y,B3.y};
        xx1[14] = (v2f){A3.z,B3.z}; xx1[15] = (v2f){A3.w,B3.w};
        x2[0][0]=A4.x;  x2[0][1]=A4.y;  x2[0][2]=A4.z;  x2[0][3]=A4.w;
        x2[0][4]=A5.x;  x2[0][5]=A5.y;  x2[0][6]=A5.z;  x2[0][7]=A5.w;
        x2[0][8]=A6.x;  x2[0][9]=A6.y;  x2[0][10]=A6.z; x2[0][11]=A6.w;
        x2[0][12]=A7.x; x2[0][13]=A7.y; x2[0][14]=A7.z; x2[0][15]=A7.w;
        x2[1][0]=B4.x;  x2[1][1]=B4.y;  x2[1][2]=B4.z;  x2[1][3]=B4.w;
        x2[1][4]=B5.x;  x2[1][5]=B5.y;  x2[1][6]=B5.z;  x2[1][7]=B5.w;
        x2[1][8]=B6.x;  x2[1][9]=B6.y;  x2[1][10]=B6.z; x2[1][11]=B6.w;
        x2[1][12]=B7.x; x2[1][13]=B7.y; x2[1][14]=B7.z; x2[1][15]=B7.w;
    }

    // ---- Phase 1: outer argmin. Raw centers via wave-uniform s_load (scalar pipe,
    //      zero VALU cost), software-pipelined cur/nxt. Norm seeds the pk_fma chain. ----
    float bd0 = 3.4e38f, bd1 = 3.4e38f;
    int bo0 = 0, bo1 = 0;

    float cur[D];
#pragma unroll
    for (int k = 0; k < D; ++k) cur[k] = co[k];

#pragma unroll 2
    for (int j = 0; j < NC; ++j) {
        float nxt[D];
        int jn = (j < NC - 1) ? (j + 1) : j;
#pragma unroll
        for (int k = 0; k < D; ++k) nxt[k] = co[jn * D + k];   // uniform -> s_load, indep of compute

        float nrm = lane_bcast(mynorm, j);                      // 0.5*||c_j||^2
        v2f acc = (v2f){nrm, nrm};
#pragma unroll
        for (int k = 0; k < D; ++k)
            acc = __builtin_elementwise_fma(-xx1[k], (v2f){cur[k], cur[k]}, acc); // neg-mod, free

        if (acc.x < bd0) { bd0 = acc.x; bo0 = j; }   // strict <: np.argmin first-index ties
        if (acc.y < bd1) { bd1 = acc.y; bo1 = j; }

#pragma unroll
        for (int k = 0; k < D; ++k) cur[k] = nxt[k];            // SGPR rotate (scalar pipe)
    }

    // ---- Phase 2: inner argmin (LDS gather by per-lane bo). Same seeding trick. ----
    int boA[2] = {bo0, bo1};
    int pA[2]  = {p0, p1};
    bool vA[2] = {v0, v1};
#pragma unroll
    for (int pt = 0; pt < 2; ++pt) {
        const float* cb = s_ci + boA[pt] * OSTRIDE;
        const float* nb = s_inorm + boA[pt] * 9;
        float nrm8[NCPC];
#pragma unroll
        for (int k = 0; k < NCPC; ++k) nrm8[k] = nb[k];         // 8 ds_read_b32, issued early
        float bd = 3.4e38f; int bk = 0;
#pragma unroll
        for (int k = 0; k < NCPC; ++k) {
            float4 c0 = *(const float4*)&cb[k * D + 0];
            float4 c1 = *(const float4*)&cb[k * D + 4];
            float4 c2 = *(const float4*)&cb[k * D + 8];
            float4 c3 = *(const float4*)&cb[k * D + 12];
            float acc = nrm8[k];                                // 0.5*||ci||^2 seeds chain
            acc = fmaf(-x2[pt][0],  c0.x, acc); acc = fmaf(-x2[pt][1],  c0.y, acc);
            acc = fmaf(-x2[pt][2],  c0.z, acc); acc = fmaf(-x2[pt][3],  c0.w, acc);
            acc = fmaf(-x2[pt][4],  c1.x, acc); acc = fmaf(-x2[pt][5],  c1.y, acc);
            acc = fmaf(-x2[pt][6],  c1.z, acc); acc = fmaf(-x2[pt][7],  c1.w, acc);
            acc = fmaf(-x2[pt][8],  c2.x, acc); acc = fmaf(-x2[pt][9],  c2.y, acc);
            acc = fmaf(-x2[pt][10], c2.z, acc); acc = fmaf(-x2[pt][11], c2.w, acc);
            acc = fmaf(-x2[pt][12], c3.x, acc); acc = fmaf(-x2[pt][13], c3.y, acc);
            acc = fmaf(-x2[pt][14], c3.z, acc); acc = fmaf(-x2[pt][15], c3.w, acc);
            if (acc < bd) { bd = acc; bk = k; }
        }
        if (vA[pt]) out[pA[pt]] = boA[pt] * NCPC + bk;
    }
}

extern "C" void kernel_launch(void* const* d_in, const int* in_sizes, int n_in,
                              void* d_out, int out_size, void* d_ws, size_t ws_size,
                              hipStream_t stream) {
    const float* x  = (const float*)d_in[0];   // (N, 32) fp32
    const float* co = (const float*)d_in[1];   // (64, 16) fp32
    const float* ci = (const float*)d_in[2];   // (64, 8, 16) fp32
    int* out = (int*)d_out;                    // (N,) int32
    int n = in_sizes[0] / 32;
    int blocks = (n + BLOCK * NPT - 1) / (BLOCK * NPT);
    cluster_kernel<<<blocks, BLOCK, 0, stream>>>(x, co, ci, out, n);
}